// Round 1
// baseline (153.763 us; speedup 1.0000x reference)
//
#include <hip/hip_runtime.h>
#include <hip/hip_bf16.h>

// KoLeo loss, B=8192, D=256, TOPK=1.
// loss = mean_i( -log( ||x_i - x_{nn(i)}|| + 2*EPS ) ),  x = row-normalize(input)
// nn(i) = argmax_{j!=i} dot(x_i, x_j)   (cosine NN since rows ~unit)

#define NB 8192
#define ND 256
#define EPSF 1e-8f

typedef __attribute__((ext_vector_type(8))) short short8;
typedef __attribute__((ext_vector_type(4))) float f32x4;

__device__ __forceinline__ unsigned short f2bf(float f) {
    unsigned int u = __float_as_uint(f);
    unsigned int r = (u + 0x7FFFu + ((u >> 16) & 1u)) >> 16;   // RNE
    return (unsigned short)r;
}

__device__ __forceinline__ unsigned int fkey(float f) {
    // order-preserving float -> uint (all real keys here > 0)
    unsigned int u = __float_as_uint(f);
    return (u & 0x80000000u) ? ~u : (u | 0x80000000u);
}

// ---------------- Phase A: row L2-normalize, write bf16 x + norms -------------
__global__ __launch_bounds__(256) void koleo_normalize(const float* __restrict__ s,
                                                       unsigned int* __restrict__ xb_u32,
                                                       float* __restrict__ norms) {
    const int w = threadIdx.x >> 6, lane = threadIdx.x & 63;
    const int row = blockIdx.x * 4 + w;
    const float4 v = *(const float4*)(s + row * ND + lane * 4);
    float ss = v.x * v.x + v.y * v.y + v.z * v.z + v.w * v.w;
    #pragma unroll
    for (int m = 32; m; m >>= 1) ss += __shfl_xor(ss, m);
    const float nrm = sqrtf(ss);
    const float sc = 1.0f / (nrm + EPSF);
    unsigned int p0 = (unsigned int)f2bf(v.x * sc) | ((unsigned int)f2bf(v.y * sc) << 16);
    unsigned int p1 = (unsigned int)f2bf(v.z * sc) | ((unsigned int)f2bf(v.w * sc) << 16);
    uint2 pk; pk.x = p0; pk.y = p1;
    *(uint2*)(xb_u32 + (row * ND + lane * 4) / 2) = pk;
    if (lane == 0) norms[row] = nrm;
}

// ---------------- Phase B: bf16 MFMA argmax over Gram matrix ------------------
// grid (NB/128, 16); block 256 = 4 waves; wave owns 32 rows (2 x 16-row tiles);
// block scans a 512-column slice. Per 16-col tile: 8 b-loads, 16 MFMAs.
__global__ __launch_bounds__(256) void koleo_argmax(const short* __restrict__ x,
                                                    unsigned long long* __restrict__ best) {
    const int tid = threadIdx.x;
    const int w = tid >> 6, lane = tid & 63;
    const int m = lane & 15, kg = lane >> 4;
    const int rowbase = blockIdx.x * 128 + w * 32;
    const int colbase = blockIdx.y * 512;

    short8 a0[8], a1[8];
    {
        const short* ar0 = x + (rowbase + m) * ND + kg * 8;
        const short* ar1 = x + (rowbase + 16 + m) * ND + kg * 8;
        #pragma unroll
        for (int ks = 0; ks < 8; ++ks) {
            a0[ks] = *(const short8*)(ar0 + ks * 32);
            a1[ks] = *(const short8*)(ar1 + ks * 32);
        }
    }

    float bd0[4] = {-2.f, -2.f, -2.f, -2.f}, bd1[4] = {-2.f, -2.f, -2.f, -2.f};
    int   bi0[4] = {0, 0, 0, 0},             bi1[4] = {0, 0, 0, 0};

    for (int ct = 0; ct < 32; ++ct) {
        const int colstart = colbase + ct * 16;
        const short* brow = x + (colstart + m) * ND + kg * 8;
        f32x4 acc0 = {0.f, 0.f, 0.f, 0.f};
        f32x4 acc1 = {0.f, 0.f, 0.f, 0.f};
        #pragma unroll
        for (int ks = 0; ks < 8; ++ks) {
            short8 b = *(const short8*)(brow + ks * 32);
            acc0 = __builtin_amdgcn_mfma_f32_16x16x32_bf16(a0[ks], b, acc0, 0, 0, 0);
            acc1 = __builtin_amdgcn_mfma_f32_16x16x32_bf16(a1[ks], b, acc1, 0, 0, 0);
        }
        const int j = colstart + m;   // C/D: col = lane&15
        #pragma unroll
        for (int r = 0; r < 4; ++r) { // C/D: row = (lane>>4)*4 + r
            const int i0 = rowbase + kg * 4 + r;
            const float v0 = acc0[r];
            if (j != i0 && (v0 > bd0[r] || (v0 == bd0[r] && j < bi0[r]))) { bd0[r] = v0; bi0[r] = j; }
            const int i1 = rowbase + 16 + kg * 4 + r;
            const float v1 = acc1[r];
            if (j != i1 && (v1 > bd1[r] || (v1 == bd1[r] && j < bi1[r]))) { bd1[r] = v1; bi1[r] = j; }
        }
    }

    // reduce across the 16 lanes (same kg) holding one row's 16 column slots
    #pragma unroll
    for (int r = 0; r < 4; ++r) {
        float v0 = bd0[r]; int j0 = bi0[r];
        float v1 = bd1[r]; int j1 = bi1[r];
        #pragma unroll
        for (int mask = 1; mask < 16; mask <<= 1) {
            float ov0 = __shfl_xor(v0, mask); int oj0 = __shfl_xor(j0, mask);
            if (ov0 > v0 || (ov0 == v0 && oj0 < j0)) { v0 = ov0; j0 = oj0; }
            float ov1 = __shfl_xor(v1, mask); int oj1 = __shfl_xor(j1, mask);
            if (ov1 > v1 || (ov1 == v1 && oj1 < j1)) { v1 = ov1; j1 = oj1; }
        }
        if (m == 0) {
            const int i0 = rowbase + kg * 4 + r;
            unsigned long long p0 = ((unsigned long long)fkey(v0) << 32) | (unsigned int)j0;
            atomicMax(&best[i0], p0);
            const int i1 = rowbase + 16 + kg * 4 + r;
            unsigned long long p1 = ((unsigned long long)fkey(v1) << 32) | (unsigned int)j1;
            atomicMax(&best[i1], p1);
        }
    }
}

// ---------------- Phase C: exact fp32 distances + partial loss sums -----------
__global__ __launch_bounds__(256) void koleo_dist(const float* __restrict__ s,
                                                  const float* __restrict__ norms,
                                                  const unsigned long long* __restrict__ best,
                                                  float* __restrict__ partial) {
    __shared__ float wsums[4];
    const int w = threadIdx.x >> 6, lane = threadIdx.x & 63;
    float acc = 0.f;
    #pragma unroll 1
    for (int t = 0; t < 16; ++t) {
        const int i = blockIdx.x * 64 + w * 16 + t;
        const int j = (int)(best[i] & 0xFFFFFFFFull);
        const float sci = 1.0f / (norms[i] + EPSF);
        const float scj = 1.0f / (norms[j] + EPSF);
        const float4 vi = *(const float4*)(s + i * ND + lane * 4);
        const float4 vj = *(const float4*)(s + j * ND + lane * 4);
        const float dx = vi.x * sci - vj.x * scj;
        const float dy = vi.y * sci - vj.y * scj;
        const float dz = vi.z * sci - vj.z * scj;
        const float dw = vi.w * sci - vj.w * scj;
        float d2 = dx * dx + dy * dy + dz * dz + dw * dw;
        #pragma unroll
        for (int mask = 32; mask; mask >>= 1) d2 += __shfl_xor(d2, mask);
        // distances = norm + EPS; loss term = -log(distances + EPS)
        acc += -logf(sqrtf(d2) + EPSF + EPSF);
    }
    if (lane == 0) wsums[w] = acc;
    __syncthreads();
    if (threadIdx.x == 0) partial[blockIdx.x] = wsums[0] + wsums[1] + wsums[2] + wsums[3];
}

// ---------------- Phase D: final reduce ---------------------------------------
__global__ __launch_bounds__(128) void koleo_final(const float* __restrict__ partial,
                                                   float* __restrict__ out) {
    float v = partial[threadIdx.x];   // 128 partials, 128 threads
    #pragma unroll
    for (int mask = 32; mask; mask >>= 1) v += __shfl_xor(v, mask);
    __shared__ float w2[2];
    if ((threadIdx.x & 63) == 0) w2[threadIdx.x >> 6] = v;
    __syncthreads();
    if (threadIdx.x == 0) out[0] = (w2[0] + w2[1]) / (float)NB;
}

extern "C" void kernel_launch(void* const* d_in, const int* in_sizes, int n_in,
                              void* d_out, int out_size, void* d_ws, size_t ws_size,
                              hipStream_t stream) {
    const float* s = (const float*)d_in[0];
    float* out = (float*)d_out;
    char* ws = (char*)d_ws;

    // ws layout
    unsigned int* xb = (unsigned int*)ws;                                  // 4 MiB bf16 x
    float* norms = (float*)(ws + 4 * 1024 * 1024);                         // 32 KiB
    unsigned long long* best = (unsigned long long*)(ws + 4 * 1024 * 1024 + 32 * 1024); // 64 KiB
    float* partial = (float*)(ws + 4 * 1024 * 1024 + 96 * 1024);           // 512 B

    // best must be zeroed every call (atomicMax merge; ws is poisoned once)
    hipMemsetAsync(best, 0, NB * sizeof(unsigned long long), stream);

    koleo_normalize<<<NB / 4, 256, 0, stream>>>(s, xb, norms);
    koleo_argmax<<<dim3(NB / 128, 16), 256, 0, stream>>>((const short*)xb, best);
    koleo_dist<<<NB / 64, 256, 0, stream>>>(s, norms, best, partial);
    koleo_final<<<1, 128, 0, stream>>>(partial, out);
}

// Round 2
// 88.575 us; speedup vs baseline: 1.7360x; 1.7360x over previous
//
#include <hip/hip_runtime.h>
#include <hip/hip_bf16.h>

// KoLeo loss, B=8192, D=256, TOPK=1.
// loss = mean_i( -log( ||x_i - x_{nn(i)}|| + 2*EPS ) ),  x = row-normalize(input)
// nn(i) = argmax_{j!=i} dot(x_i, x_j)  via bf16 MFMA Gram scan (selection only);
// the selected distance is recomputed exactly in fp32.

#define NB 8192
#define ND 256
#define EPSF 1e-8f
#define CSL 512            // column slice per block

typedef __attribute__((ext_vector_type(8))) short short8;
typedef __attribute__((ext_vector_type(4))) float f32x4;
typedef unsigned long long ull;

__device__ __forceinline__ unsigned short f2bf(float f) {
    unsigned int u = __float_as_uint(f);
    unsigned int r = (u + 0x7FFFu + ((u >> 16) & 1u)) >> 16;   // RNE
    return (unsigned short)r;
}

__device__ __forceinline__ unsigned int fkey(float f) {
    unsigned int u = __float_as_uint(f);
    return (u & 0x80000000u) ? ~u : (u | 0x80000000u);
}

// ---------------- Phase A: row L2-normalize -> bf16 x, norms; zero `best` ----
__global__ __launch_bounds__(256) void koleo_normalize(const float* __restrict__ s,
                                                       unsigned int* __restrict__ xb_u32,
                                                       float* __restrict__ norms,
                                                       ull* __restrict__ best) {
    const int w = threadIdx.x >> 6, lane = threadIdx.x & 63;
    const int row = blockIdx.x * 4 + w;
    const float4 v = *(const float4*)(s + row * ND + lane * 4);
    float ss = v.x * v.x + v.y * v.y + v.z * v.z + v.w * v.w;
    #pragma unroll
    for (int m = 32; m; m >>= 1) ss += __shfl_xor(ss, m);
    const float nrm = sqrtf(ss);
    const float sc = 1.0f / (nrm + EPSF);
    uint2 pk;
    pk.x = (unsigned int)f2bf(v.x * sc) | ((unsigned int)f2bf(v.y * sc) << 16);
    pk.y = (unsigned int)f2bf(v.z * sc) | ((unsigned int)f2bf(v.w * sc) << 16);
    *(uint2*)(xb_u32 + (row * ND + lane * 4) / 2) = pk;
    if (lane == 0) { norms[row] = nrm; best[row] = 0ull; }
}

// ---------------- Phase B: bf16 MFMA argmax over Gram matrix ------------------
// grid (NB/256, NB/CSL); block 256 = 4 waves; wave owns 64 rows (4 row-tiles).
// Inner iter: 32 cols (2 col-groups) -> 8 independent MFMA chains, 32 MFMA / 16 loads.
__global__ __launch_bounds__(256) void koleo_argmax(const short* __restrict__ x,
                                                    ull* __restrict__ best) {
    const int tid = threadIdx.x;
    const int w = tid >> 6, lane = tid & 63;
    const int m = lane & 15, kg = lane >> 4;
    const int rowbase = blockIdx.x * 256 + w * 64;
    const int colbase = blockIdx.y * CSL;

    // A fragments: 4 row-tiles x 8 k-steps (128 regs)
    short8 a[4][8];
    #pragma unroll
    for (int rt = 0; rt < 4; ++rt) {
        const short* ar = x + (rowbase + rt * 16 + m) * ND + kg * 8;
        #pragma unroll
        for (int ks = 0; ks < 8; ++ks) a[rt][ks] = *(const short8*)(ar + ks * 32);
    }

    float bd[4][4];
    int   bi[4][4];
    #pragma unroll
    for (int rt = 0; rt < 4; ++rt)
        #pragma unroll
        for (int r = 0; r < 4; ++r) { bd[rt][r] = -2.f; bi[rt][r] = 0; }

    for (int ct = 0; ct < CSL / 32; ++ct) {
        const int colstart = colbase + ct * 32;
        const short* b0p = x + (colstart + m) * ND + kg * 8;
        const short* b1p = b0p + 16 * ND;

        f32x4 acc[4][2];
        #pragma unroll
        for (int rt = 0; rt < 4; ++rt) {
            acc[rt][0] = (f32x4){0.f, 0.f, 0.f, 0.f};
            acc[rt][1] = (f32x4){0.f, 0.f, 0.f, 0.f};
        }
        #pragma unroll
        for (int ks = 0; ks < 8; ++ks) {
            const short8 b0 = *(const short8*)(b0p + ks * 32);
            const short8 b1 = *(const short8*)(b1p + ks * 32);
            #pragma unroll
            for (int rt = 0; rt < 4; ++rt) {
                acc[rt][0] = __builtin_amdgcn_mfma_f32_16x16x32_bf16(a[rt][ks], b0, acc[rt][0], 0, 0, 0);
                acc[rt][1] = __builtin_amdgcn_mfma_f32_16x16x32_bf16(a[rt][ks], b1, acc[rt][1], 0, 0, 0);
            }
        }
        // argmax epilogue: C/D layout col = lane&15, row = kg*4 + r
        #pragma unroll
        for (int cg = 0; cg < 2; ++cg) {
            const int j = colstart + cg * 16 + m;
            #pragma unroll
            for (int rt = 0; rt < 4; ++rt) {
                #pragma unroll
                for (int r = 0; r < 4; ++r) {
                    const int i = rowbase + rt * 16 + kg * 4 + r;
                    const float v = acc[rt][cg][r];
                    if (j != i && v > bd[rt][r]) { bd[rt][r] = v; bi[rt][r] = j; }
                }
            }
        }
    }

    // reduce across the 16 lanes (same kg) holding one row's 16 column slots
    #pragma unroll
    for (int rt = 0; rt < 4; ++rt) {
        #pragma unroll
        for (int r = 0; r < 4; ++r) {
            float v = bd[rt][r]; int j = bi[rt][r];
            #pragma unroll
            for (int mask = 1; mask < 16; mask <<= 1) {
                float ov = __shfl_xor(v, mask); int oj = __shfl_xor(j, mask);
                if (ov > v || (ov == v && oj < j)) { v = ov; j = oj; }
            }
            if (m == 0) {
                const int i = rowbase + rt * 16 + kg * 4 + r;
                atomicMax(&best[i], ((ull)fkey(v) << 32) | (unsigned int)j);
            }
        }
    }
}

// ---------------- Phase C: exact fp32 distances + partial loss sums -----------
// grid NB/16 = 512 blocks; 4 waves/block; each wave handles 4 rows.
__global__ __launch_bounds__(256) void koleo_dist(const float* __restrict__ s,
                                                  const float* __restrict__ norms,
                                                  const ull* __restrict__ best,
                                                  float* __restrict__ partial) {
    __shared__ float wsums[4];
    const int w = threadIdx.x >> 6, lane = threadIdx.x & 63;
    float acc = 0.f;
    #pragma unroll
    for (int t = 0; t < 4; ++t) {
        const int i = blockIdx.x * 16 + w * 4 + t;
        const int j = (int)(best[i] & 0xFFFFFFFFull);
        const float sci = 1.0f / (norms[i] + EPSF);
        const float scj = 1.0f / (norms[j] + EPSF);
        const float4 vi = *(const float4*)(s + i * ND + lane * 4);
        const float4 vj = *(const float4*)(s + j * ND + lane * 4);
        const float dx = vi.x * sci - vj.x * scj;
        const float dy = vi.y * sci - vj.y * scj;
        const float dz = vi.z * sci - vj.z * scj;
        const float dw = vi.w * sci - vj.w * scj;
        float d2 = dx * dx + dy * dy + dz * dz + dw * dw;
        #pragma unroll
        for (int mask = 32; mask; mask >>= 1) d2 += __shfl_xor(d2, mask);
        // distances = ||.|| + EPS; loss term = -log(distances + EPS)
        acc += -logf(sqrtf(d2) + EPSF + EPSF);
    }
    if (lane == 0) wsums[w] = acc;
    __syncthreads();
    if (threadIdx.x == 0) partial[blockIdx.x] = wsums[0] + wsums[1] + wsums[2] + wsums[3];
}

// ---------------- Phase D: final reduce (512 partials) ------------------------
__global__ __launch_bounds__(512) void koleo_final(const float* __restrict__ partial,
                                                   float* __restrict__ out) {
    __shared__ float w8[8];
    float v = partial[threadIdx.x];
    #pragma unroll
    for (int mask = 32; mask; mask >>= 1) v += __shfl_xor(v, mask);
    if ((threadIdx.x & 63) == 0) w8[threadIdx.x >> 6] = v;
    __syncthreads();
    if (threadIdx.x == 0) {
        float t = 0.f;
        #pragma unroll
        for (int k = 0; k < 8; ++k) t += w8[k];
        out[0] = t / (float)NB;
    }
}

extern "C" void kernel_launch(void* const* d_in, const int* in_sizes, int n_in,
                              void* d_out, int out_size, void* d_ws, size_t ws_size,
                              hipStream_t stream) {
    const float* s = (const float*)d_in[0];
    float* out = (float*)d_out;
    char* ws = (char*)d_ws;

    // ws layout
    unsigned int* xb = (unsigned int*)ws;                                   // 4 MiB bf16 x
    float* norms = (float*)(ws + 4 * 1024 * 1024);                          // 32 KiB
    ull* best = (ull*)(ws + 4 * 1024 * 1024 + 32 * 1024);                   // 64 KiB
    float* partial = (float*)(ws + 4 * 1024 * 1024 + 96 * 1024);            // 2 KiB

    koleo_normalize<<<NB / 4, 256, 0, stream>>>(s, xb, norms, best);
    koleo_argmax<<<dim3(NB / 256, NB / CSL), 256, 0, stream>>>((const short*)xb, best);
    koleo_dist<<<NB / 16, 256, 0, stream>>>(s, norms, best, partial);
    koleo_final<<<1, 512, 0, stream>>>(partial, out);
}

// Round 3
// 54.540 us; speedup vs baseline: 2.8192x; 1.6240x over previous
//
#include <hip/hip_runtime.h>
#include <hip/hip_bf16.h>

// KoLeo loss, B=8192, D=256, TOPK=1.
// loss = mean_i( -log( ||x_i - x_{nn(i)}|| + 2*EPS ) ),  x = row-normalize(input)
// nn(i) = argmax_{j!=i} dot(x_i, x_j)  via bf16 MFMA Gram scan (selection only);
// the selected distance is recomputed exactly in fp32.
//
// argmax kernel: swapped-operand 32x32x16 MFMA. Wave holds 32 OWNED columns as
// the B operand in registers (K=256 -> 16 frags); streamed rows are the A
// operand, staged through double-buffered XOR-swizzled LDS shared by 4 waves.
// C layout col=lane&31 => one running (best,idx) per lane; final reduce is a
// single shfl_xor(32) across the two k-halves.

#define NB 8192
#define ND 256
#define ROWB 512          // bytes per row of bf16 x
#define EPSF 1e-8f
#define OWN 128           // owned cols per block (32 per wave)
#define CSL 512           // streamed rows per block
#define TROWS 32          // streamed rows per LDS tile (16 KB)
#define NT (CSL / TROWS)  // 16 tiles

typedef __attribute__((ext_vector_type(8))) short short8;
typedef __attribute__((ext_vector_type(16))) float f32x16;
typedef unsigned long long ull;

__device__ __forceinline__ unsigned short f2bf(float f) {
    unsigned int u = __float_as_uint(f);
    unsigned int r = (u + 0x7FFFu + ((u >> 16) & 1u)) >> 16;   // RNE
    return (unsigned short)r;
}

__device__ __forceinline__ unsigned int fkey(float f) {
    unsigned int u = __float_as_uint(f);
    return (u & 0x80000000u) ? ~u : (u | 0x80000000u);
}

__device__ __forceinline__ void gload16(const void* g, void* l) {
    __builtin_amdgcn_global_load_lds(
        (const __attribute__((address_space(1))) unsigned int*)g,
        (__attribute__((address_space(3))) unsigned int*)l,
        16, 0, 0);
}

// ---------------- Phase A: row L2-normalize -> bf16 x, norms; zero `best` ----
__global__ __launch_bounds__(256) void koleo_normalize(const float* __restrict__ s,
                                                       unsigned int* __restrict__ xb_u32,
                                                       float* __restrict__ norms,
                                                       ull* __restrict__ best) {
    const int w = threadIdx.x >> 6, lane = threadIdx.x & 63;
    const int row = blockIdx.x * 4 + w;
    const float4 v = *(const float4*)(s + row * ND + lane * 4);
    float ss = v.x * v.x + v.y * v.y + v.z * v.z + v.w * v.w;
    #pragma unroll
    for (int m = 32; m; m >>= 1) ss += __shfl_xor(ss, m);
    const float nrm = sqrtf(ss);
    const float sc = 1.0f / (nrm + EPSF);
    uint2 pk;
    pk.x = (unsigned int)f2bf(v.x * sc) | ((unsigned int)f2bf(v.y * sc) << 16);
    pk.y = (unsigned int)f2bf(v.z * sc) | ((unsigned int)f2bf(v.w * sc) << 16);
    *(uint2*)(xb_u32 + (row * ND + lane * 4) / 2) = pk;
    if (lane == 0) { norms[row] = nrm; best[row] = 0ull; }
}

// ---------------- Phase B: swapped-operand MFMA argmax ------------------------
// grid (NB/OWN, NB/CSL) = (64, 16); block 256 = 4 waves.
__global__ __launch_bounds__(256) void koleo_argmax(const short* __restrict__ x,
                                                    ull* __restrict__ best) {
    __shared__ short lds[2][TROWS * ND];   // 2 x 16 KB double buffer
    const int tid = threadIdx.x;
    const int lane = tid & 63;
    const int col = lane & 31;             // owned col within wave / A row / D col
    const int h = lane >> 5;               // k-half selector
    const int i = blockIdx.x * OWN + (tid >> 6) * 32 + col;   // this lane's owned col
    const int sbase = blockIdx.y * CSL;
    const char* xc = (const char*)x;

    // owned-col B fragments: col i, 16 k-steps x 8 bf16 (64 VGPRs)
    short8 bfrag[16];
    {
        const short* bp = x + (size_t)i * ND + h * 8;
        #pragma unroll
        for (int ks = 0; ks < 16; ++ks) bfrag[ks] = *(const short8*)(bp + ks * 16);
    }

    // staging: thread stages 4 x 16B chunks/tile; LDS linear, global pre-swizzled
    int soff[4];
    #pragma unroll
    for (int ph = 0; ph < 4; ++ph) {
        const int idx = ph * 256 + tid;
        const int row = idx >> 5, c16 = idx & 31;
        soff[ph] = row * ROWB + ((c16 ^ (row & 7)) << 4);
    }
    const int ldsoff = tid << 4;

    // A-fragment ds_read addressing (swizzled on read with the same involution)
    const int abase = col * ROWB;
    const int hx = (h << 4) ^ ((col & 7) << 4);

    float bd = -2.0f;
    int bi = 0;
    char* l0 = (char*)&lds[0][0];

    // prologue: stage tile 0
    {
        const char* gt = xc + (size_t)sbase * ROWB;
        #pragma unroll
        for (int ph = 0; ph < 4; ++ph)
            gload16(gt + soff[ph], l0 + ph * 4096 + ldsoff);
    }
    __syncthreads();

    for (int t = 0; t < NT; ++t) {
        const int cur = t & 1;
        // issue next-tile staging BEFORE compute (overlaps; drained at barrier)
        if (t + 1 < NT) {
            const char* gt = xc + (size_t)(sbase + (t + 1) * TROWS) * ROWB;
            char* lb = l0 + (cur ^ 1) * 16384;
            #pragma unroll
            for (int ph = 0; ph < 4; ++ph)
                gload16(gt + soff[ph], lb + ph * 4096 + ldsoff);
        }
        const char* lt = l0 + cur * 16384;
        f32x16 acc;
        #pragma unroll
        for (int z = 0; z < 16; ++z) acc[z] = 0.f;
        #pragma unroll
        for (int ks = 0; ks < 16; ++ks) {
            const short8 a = *(const short8*)(lt + abase + (hx ^ (ks << 5)));
            acc = __builtin_amdgcn_mfma_f32_32x32x16_bf16(a, bfrag[ks], acc, 0, 0, 0);
        }
        // argmax epilogue: D row (streamed j) = (r&3) + 8*(r>>2) + 4*h
        const int jb = sbase + t * TROWS + 4 * h;
        #pragma unroll
        for (int r = 0; r < 16; ++r) {
            const int j = jb + (r & 3) + 8 * (r >> 2);
            const float v = acc[r];
            if (j != i && v > bd) { bd = v; bi = j; }
        }
        __syncthreads();
    }

    // reduce across the two k-halves and merge globally
    {
        const float ov = __shfl_xor(bd, 32);
        const int oj = __shfl_xor(bi, 32);
        if (ov > bd || (ov == bd && oj < bi)) { bd = ov; bi = oj; }
        if (lane < 32) atomicMax(&best[i], ((ull)fkey(bd) << 32) | (unsigned int)bi);
    }
}

// ---------------- Phase C: exact fp32 distances + partial loss sums -----------
// grid NB/16 = 512 blocks; 4 waves/block; each wave handles 4 rows.
__global__ __launch_bounds__(256) void koleo_dist(const float* __restrict__ s,
                                                  const float* __restrict__ norms,
                                                  const ull* __restrict__ best,
                                                  float* __restrict__ partial) {
    __shared__ float wsums[4];
    const int w = threadIdx.x >> 6, lane = threadIdx.x & 63;
    float acc = 0.f;
    #pragma unroll
    for (int t = 0; t < 4; ++t) {
        const int i = blockIdx.x * 16 + w * 4 + t;
        const int j = (int)(best[i] & 0xFFFFFFFFull);
        const float sci = 1.0f / (norms[i] + EPSF);
        const float scj = 1.0f / (norms[j] + EPSF);
        const float4 vi = *(const float4*)(s + i * ND + lane * 4);
        const float4 vj = *(const float4*)(s + j * ND + lane * 4);
        const float dx = vi.x * sci - vj.x * scj;
        const float dy = vi.y * sci - vj.y * scj;
        const float dz = vi.z * sci - vj.z * scj;
        const float dw = vi.w * sci - vj.w * scj;
        float d2 = dx * dx + dy * dy + dz * dz + dw * dw;
        #pragma unroll
        for (int mask = 32; mask; mask >>= 1) d2 += __shfl_xor(d2, mask);
        acc += -logf(sqrtf(d2) + EPSF + EPSF);
    }
    if (lane == 0) wsums[w] = acc;
    __syncthreads();
    if (threadIdx.x == 0) partial[blockIdx.x] = wsums[0] + wsums[1] + wsums[2] + wsums[3];
}

// ---------------- Phase D: final reduce (512 partials) ------------------------
__global__ __launch_bounds__(512) void koleo_final(const float* __restrict__ partial,
                                                   float* __restrict__ out) {
    __shared__ float w8[8];
    float v = partial[threadIdx.x];
    #pragma unroll
    for (int mask = 32; mask; mask >>= 1) v += __shfl_xor(v, mask);
    if ((threadIdx.x & 63) == 0) w8[threadIdx.x >> 6] = v;
    __syncthreads();
    if (threadIdx.x == 0) {
        float t = 0.f;
        #pragma unroll
        for (int k = 0; k < 8; ++k) t += w8[k];
        out[0] = t / (float)NB;
    }
}

extern "C" void kernel_launch(void* const* d_in, const int* in_sizes, int n_in,
                              void* d_out, int out_size, void* d_ws, size_t ws_size,
                              hipStream_t stream) {
    const float* s = (const float*)d_in[0];
    float* out = (float*)d_out;
    char* ws = (char*)d_ws;

    // ws layout
    unsigned int* xb = (unsigned int*)ws;                                   // 4 MiB bf16 x
    float* norms = (float*)(ws + 4 * 1024 * 1024);                          // 32 KiB
    ull* best = (ull*)(ws + 4 * 1024 * 1024 + 32 * 1024);                   // 64 KiB
    float* partial = (float*)(ws + 4 * 1024 * 1024 + 96 * 1024);            // 2 KiB

    koleo_normalize<<<NB / 4, 256, 0, stream>>>(s, xb, norms, best);
    koleo_argmax<<<dim3(NB / OWN, NB / CSL), 256, 0, stream>>>((const short*)xb, best);
    koleo_dist<<<NB / 16, 256, 0, stream>>>(s, norms, best, partial);
    koleo_final<<<1, 512, 0, stream>>>(partial, out);
}

// Round 4
// 54.324 us; speedup vs baseline: 2.8305x; 1.0040x over previous
//
#include <hip/hip_runtime.h>
#include <hip/hip_bf16.h>

// KoLeo loss, B=8192, D=256, TOPK=1.
// loss = mean_i( -log( ||x_i - x_{nn(i)}|| + 2*EPS ) ),  x = row-normalize(input)
// nn(i) = argmax_{j!=i} dot(x_i, x_j)  via bf16 MFMA Gram scan (selection only);
// the selected distance is recomputed exactly in fp32.
//
// argmax kernel: swapped-operand 32x32x16 MFMA. Each wave holds 64 OWNED
// columns as TWO B-operand register sets (K=256 -> 2x16 frags, 128 VGPRs);
// streamed rows are the A operand, staged through double-buffered LDS shared
// by 4 waves. Each A ds_read feeds 2 MFMAs -> LDS read traffic halved vs the
// 32-col version (that one was LDS-BW-bound). 5-bit XOR swizzle (slot ^= row)
// on both the pre-swizzled global staging source and the ds_read address
// kills the 4-way bank conflict (linear dest for global_load_lds, G21).
// C layout col=lane&31 => one running (best,idx) per lane per col-set.

#define NB 8192
#define ND 256
#define ROWB 512          // bytes per row of bf16 x
#define EPSF 1e-8f
#define OWN 256           // owned cols per block (64 per wave)
#define CSL 512           // streamed rows per block slice
#define TROWS 32          // streamed rows per LDS tile (16 KB)
#define NT (CSL / TROWS)  // 16 tiles

typedef __attribute__((ext_vector_type(8))) short short8;
typedef __attribute__((ext_vector_type(16))) float f32x16;
typedef unsigned long long ull;

__device__ __forceinline__ unsigned short f2bf(float f) {
    unsigned int u = __float_as_uint(f);
    unsigned int r = (u + 0x7FFFu + ((u >> 16) & 1u)) >> 16;   // RNE
    return (unsigned short)r;
}

__device__ __forceinline__ unsigned int fkey(float f) {
    unsigned int u = __float_as_uint(f);
    return (u & 0x80000000u) ? ~u : (u | 0x80000000u);
}

__device__ __forceinline__ void gload16(const void* g, void* l) {
    __builtin_amdgcn_global_load_lds(
        (const __attribute__((address_space(1))) unsigned int*)g,
        (__attribute__((address_space(3))) unsigned int*)l,
        16, 0, 0);
}

// ---------------- Phase A: row L2-normalize -> bf16 x, norms; zero `best` ----
__global__ __launch_bounds__(256) void koleo_normalize(const float* __restrict__ s,
                                                       unsigned int* __restrict__ xb_u32,
                                                       float* __restrict__ norms,
                                                       ull* __restrict__ best) {
    const int w = threadIdx.x >> 6, lane = threadIdx.x & 63;
    const int row = blockIdx.x * 4 + w;
    const float4 v = *(const float4*)(s + row * ND + lane * 4);
    float ss = v.x * v.x + v.y * v.y + v.z * v.z + v.w * v.w;
    #pragma unroll
    for (int m = 32; m; m >>= 1) ss += __shfl_xor(ss, m);
    const float nrm = sqrtf(ss);
    const float sc = 1.0f / (nrm + EPSF);
    uint2 pk;
    pk.x = (unsigned int)f2bf(v.x * sc) | ((unsigned int)f2bf(v.y * sc) << 16);
    pk.y = (unsigned int)f2bf(v.z * sc) | ((unsigned int)f2bf(v.w * sc) << 16);
    *(uint2*)(xb_u32 + (row * ND + lane * 4) / 2) = pk;
    if (lane == 0) { norms[row] = nrm; best[row] = 0ull; }
}

// ---------------- Phase B: swapped-operand MFMA argmax ------------------------
// grid (NB/OWN, NB/CSL) = (32, 16); block 256 = 4 waves; 2 blocks/CU.
__global__ __launch_bounds__(256, 2) void koleo_argmax(const short* __restrict__ x,
                                                       ull* __restrict__ best) {
    __shared__ short lds[2][TROWS * ND];   // 2 x 16 KB double buffer
    const int tid = threadIdx.x;
    const int lane = tid & 63;
    const int col = lane & 31;             // A row (streamed) / D col (owned)
    const int h = lane >> 5;               // k-half selector
    const int i0 = blockIdx.x * OWN + (tid >> 6) * 64 + col;  // owned col, set 0
    const int i1 = i0 + 32;                                   // owned col, set 1
    const int sbase = blockIdx.y * CSL;
    const bool hasdiag = ((int)blockIdx.y == ((int)blockIdx.x >> 1));
    const char* xc = (const char*)x;

    // owned-col B fragments: 2 sets x 16 k-steps x 8 bf16 (128 VGPRs)
    short8 bfrag[2][16];
    #pragma unroll
    for (int q = 0; q < 2; ++q) {
        const short* bp = x + (size_t)(i0 + 32 * q) * ND + h * 8;
        #pragma unroll
        for (int ks = 0; ks < 16; ++ks) bfrag[q][ks] = *(const short8*)(bp + ks * 16);
    }

    // staging: thread stages 4 x 16B chunks/tile; LDS dest linear,
    // global source pre-swizzled with slot ^= row (5-bit involution)
    int soff[4];
    #pragma unroll
    for (int ph = 0; ph < 4; ++ph) {
        const int idx = ph * 256 + tid;
        const int row = idx >> 5, c16 = idx & 31;
        soff[ph] = row * ROWB + ((c16 ^ row) << 4);
    }
    const int ldsoff = tid << 4;

    // A-fragment ds_read addressing: row=col, slot=(h|ks<<1) ^ col (same involution)
    const int abase = col * ROWB;
    const int colx = col << 4;

    float bd0 = -2.0f, bd1 = -2.0f;
    int bi0 = 0, bi1 = 0;
    char* l0 = (char*)&lds[0][0];

    // prologue: stage tile 0
    {
        const char* gt = xc + (size_t)sbase * ROWB;
        #pragma unroll
        for (int ph = 0; ph < 4; ++ph)
            gload16(gt + soff[ph], l0 + ph * 4096 + ldsoff);
    }
    __syncthreads();

    for (int t = 0; t < NT; ++t) {
        const int cur = t & 1;
        // issue next-tile staging BEFORE compute (drained at the barrier)
        if (t + 1 < NT) {
            const char* gt = xc + (size_t)(sbase + (t + 1) * TROWS) * ROWB;
            char* lb = l0 + (cur ^ 1) * 16384;
            #pragma unroll
            for (int ph = 0; ph < 4; ++ph)
                gload16(gt + soff[ph], lb + ph * 4096 + ldsoff);
        }
        const char* lt = l0 + cur * 16384;
        f32x16 acc0, acc1;
        #pragma unroll
        for (int z = 0; z < 16; ++z) { acc0[z] = 0.f; acc1[z] = 0.f; }
        #pragma unroll
        for (int ks = 0; ks < 16; ++ks) {
            const short8 a = *(const short8*)(lt + abase + (((ks << 5) | (h << 4)) ^ colx));
            acc0 = __builtin_amdgcn_mfma_f32_32x32x16_bf16(a, bfrag[0][ks], acc0, 0, 0, 0);
            acc1 = __builtin_amdgcn_mfma_f32_32x32x16_bf16(a, bfrag[1][ks], acc1, 0, 0, 0);
        }
        // argmax epilogue: D row (streamed j) = (r&3) + 8*(r>>2) + 4*h
        const int jb = sbase + t * TROWS + 4 * h;
        if (hasdiag) {
            #pragma unroll
            for (int r = 0; r < 16; ++r) {
                const int j = jb + (r & 3) + 8 * (r >> 2);
                const float v0 = acc0[r], v1 = acc1[r];
                if (j != i0 && v0 > bd0) { bd0 = v0; bi0 = j; }
                if (j != i1 && v1 > bd1) { bd1 = v1; bi1 = j; }
            }
        } else {
            #pragma unroll
            for (int r = 0; r < 16; ++r) {
                const int j = jb + (r & 3) + 8 * (r >> 2);
                const float v0 = acc0[r], v1 = acc1[r];
                if (v0 > bd0) { bd0 = v0; bi0 = j; }
                if (v1 > bd1) { bd1 = v1; bi1 = j; }
            }
        }
        __syncthreads();
    }

    // reduce across the two k-halves and merge globally
    {
        float ov = __shfl_xor(bd0, 32); int oj = __shfl_xor(bi0, 32);
        if (ov > bd0 || (ov == bd0 && oj < bi0)) { bd0 = ov; bi0 = oj; }
        ov = __shfl_xor(bd1, 32); oj = __shfl_xor(bi1, 32);
        if (ov > bd1 || (ov == bd1 && oj < bi1)) { bd1 = ov; bi1 = oj; }
        if (lane < 32) {
            atomicMax(&best[i0], ((ull)fkey(bd0) << 32) | (unsigned int)bi0);
            atomicMax(&best[i1], ((ull)fkey(bd1) << 32) | (unsigned int)bi1);
        }
    }
}

// ---------------- Phase C: exact fp32 distances + partial loss sums -----------
// grid NB/16 = 512 blocks; 4 waves/block; each wave handles 4 rows.
__global__ __launch_bounds__(256) void koleo_dist(const float* __restrict__ s,
                                                  const float* __restrict__ norms,
                                                  const ull* __restrict__ best,
                                                  float* __restrict__ partial) {
    __shared__ float wsums[4];
    const int w = threadIdx.x >> 6, lane = threadIdx.x & 63;
    float acc = 0.f;
    #pragma unroll
    for (int t = 0; t < 4; ++t) {
        const int i = blockIdx.x * 16 + w * 4 + t;
        const int j = (int)(best[i] & 0xFFFFFFFFull);
        const float sci = 1.0f / (norms[i] + EPSF);
        const float scj = 1.0f / (norms[j] + EPSF);
        const float4 vi = *(const float4*)(s + i * ND + lane * 4);
        const float4 vj = *(const float4*)(s + j * ND + lane * 4);
        const float dx = vi.x * sci - vj.x * scj;
        const float dy = vi.y * sci - vj.y * scj;
        const float dz = vi.z * sci - vj.z * scj;
        const float dw = vi.w * sci - vj.w * scj;
        float d2 = dx * dx + dy * dy + dz * dz + dw * dw;
        #pragma unroll
        for (int mask = 32; mask; mask >>= 1) d2 += __shfl_xor(d2, mask);
        acc += -logf(sqrtf(d2) + EPSF + EPSF);
    }
    if (lane == 0) wsums[w] = acc;
    __syncthreads();
    if (threadIdx.x == 0) partial[blockIdx.x] = wsums[0] + wsums[1] + wsums[2] + wsums[3];
}

// ---------------- Phase D: final reduce (512 partials) ------------------------
__global__ __launch_bounds__(512) void koleo_final(const float* __restrict__ partial,
                                                   float* __restrict__ out) {
    __shared__ float w8[8];
    float v = partial[threadIdx.x];
    #pragma unroll
    for (int mask = 32; mask; mask >>= 1) v += __shfl_xor(v, mask);
    if ((threadIdx.x & 63) == 0) w8[threadIdx.x >> 6] = v;
    __syncthreads();
    if (threadIdx.x == 0) {
        float t = 0.f;
        #pragma unroll
        for (int k = 0; k < 8; ++k) t += w8[k];
        out[0] = t / (float)NB;
    }
}

extern "C" void kernel_launch(void* const* d_in, const int* in_sizes, int n_in,
                              void* d_out, int out_size, void* d_ws, size_t ws_size,
                              hipStream_t stream) {
    const float* s = (const float*)d_in[0];
    float* out = (float*)d_out;
    char* ws = (char*)d_ws;

    // ws layout
    unsigned int* xb = (unsigned int*)ws;                                   // 4 MiB bf16 x
    float* norms = (float*)(ws + 4 * 1024 * 1024);                          // 32 KiB
    ull* best = (ull*)(ws + 4 * 1024 * 1024 + 32 * 1024);                   // 64 KiB
    float* partial = (float*)(ws + 4 * 1024 * 1024 + 96 * 1024);            // 2 KiB

    koleo_normalize<<<NB / 4, 256, 0, stream>>>(s, xb, norms, best);
    koleo_argmax<<<dim3(NB / OWN, NB / CSL), 256, 0, stream>>>((const short*)xb, best);
    koleo_dist<<<NB / 16, 256, 0, stream>>>(s, norms, best, partial);
    koleo_final<<<1, 512, 0, stream>>>(partial, out);
}